// Round 11
// baseline (258.969 us; speedup 1.0000x reference)
//
#include <hip/hip_runtime.h>

#define HH 64
#define WWID 64
#define CCH 32
#define HFD 96
#define WFD 320
#define NPIX (HFD*WFD)      // 30720
#define NVOX (HH*WWID*CCH)  // 131072

typedef __attribute__((ext_vector_type(8))) short short8;   // 8 bf16 (4 VGPRs)
typedef __attribute__((ext_vector_type(4))) float f32x4;

__device__ __forceinline__ float4 ld4(const float* p){ return *reinterpret_cast<const float4*>(p); }
__device__ __forceinline__ unsigned short f2bf(float f){   // RNE f32 -> bf16
  unsigned int u = __float_as_uint(f);
  return (unsigned short)((u + 0x7FFFu + ((u>>16)&1u)) >> 16);
}
__device__ __forceinline__ float bf2f(unsigned short s){
  return __uint_as_float(((unsigned int)s) << 16);
}

// ---------------- setup_all: weight tables + y-init + projection ----------------
// b in [0,256):    wt[n][k] (256x256): n<128 -> w1[k][n] ; n>=128 -> w1[259+k][n-128]
// b in [256,288):  w2t[c][k] (64x128) = w2[k][c]
// b in [288,304):  y[idx] = conv_b[0]   (4096 outputs)
// b >= 304:        projection for (v,k) pairs -> nb (1024 blocks)
__global__ __launch_bounds__(256) void setup_all(
    const float* __restrict__ P3, const float* __restrict__ R0,
    const float* __restrict__ Tr, const float* __restrict__ w1,
    const float* __restrict__ w2, const float* __restrict__ conv_b,
    const float* __restrict__ kdtree,
    unsigned short* __restrict__ wt, unsigned short* __restrict__ w2t,
    float4* __restrict__ nb, float* __restrict__ y)
{
  int b = blockIdx.x, t = threadIdx.x;
  if (b < 256){
    int e = b*256 + t;
    int n = e>>8, k = e&255;
    float v = (n<128) ? w1[k*128 + n] : w1[(259+k)*128 + (n-128)];
    wt[n*256 + k] = f2bf(v);
  } else if (b < 288){
    int e2 = (b-256)*256 + t;                // 0..8191
    int c = e2>>7, k = e2&127;
    w2t[c*128 + k] = f2bf(w2[k*64 + c]);
  } else if (b < 304){
    int idx = (b-288)*256 + t;               // 0..4095
    y[idx] = conv_b[0];
  } else {
    // projection: M computed per-block by 12 lanes (double), broadcast via LDS
    __shared__ double Ms[12];
    if (t < 12){
      int e3 = t>>2, d = t&3;
      double PRr[4];
      #pragma unroll
      for (int bb=0;bb<4;bb++){
        double s = 0.0;
        #pragma unroll
        for (int a=0;a<4;a++) s += (double)P3[e3*4+a]*(double)R0[a*4+bb];
        PRr[bb] = s;
      }
      double s = 0.0;
      #pragma unroll
      for (int bb=0;bb<4;bb++) s += PRr[bb]*(double)Tr[bb*4+d];
      Ms[t] = s;
    }
    __syncthreads();
    int gid = (b-304)*256 + t;               // 0 .. NVOX*2-1
    int v = gid>>1, k = gid&1;
    int c = v&31, w = (v>>5)&63, h = v>>11;
    size_t off = ((((size_t)(h*4)*256 + (size_t)(w*4))*32 + c)*2 + k)*4;
    float4 kp = ld4(kdtree + off);
    double k0 = kp.x, k1 = kp.y, k2 = kp.z;
    double cam0 = Ms[0]*k0 + Ms[1]*k1 + Ms[2]*k2  + Ms[3];
    double cam1 = Ms[4]*k0 + Ms[5]*k1 + Ms[6]*k2  + Ms[7];
    double cam2 = Ms[8]*k0 + Ms[9]*k1 + Ms[10]*k2 + Ms[11];
    float zf = (float)cam2;
    double zd = (fabsf(zf) < 1e-6f) ? (double)1e-6f : cam2;
    double rz = 1.0/zd;
    int ty = (int)(cam1*rz), tx = (int)(cam0*rz);   // trunc, matches astype(int32)
    int iy = ty < 0 ? 0 : ((ty>>2) > (HFD-1) ? (HFD-1) : (ty>>2));
    int ix = tx < 0 ? 0 : ((tx>>2) > (WFD-1) ? (WFD-1) : (tx>>2));
    float4 r;
    r.x = __int_as_float(iy*WFD + ix);
    r.y = kp.x - 1.0f;
    r.z = kp.y - (float)(h*4);
    r.w = kp.z - (float)(w*4);
    nb[gid] = r;
  }
}

// ---------------- pix: bf16 MFMA GEMM, pixb[30720x256](bf16) = X @ W' ----------------
// 32-row tiles (960 blocks for TLP), K=256 staged in LDS (XOR-swizzled), 4 waves split N.
__global__ __launch_bounds__(256) void pix_mfma(
    const float* __restrict__ input, const unsigned short* __restrict__ wt,
    unsigned short* __restrict__ pixb)
{
  __shared__ unsigned short sm[32*260];      // 16.6 KB: staging (16 KB swz) / epilogue 32x260
  int t = threadIdx.x;
  long pbase = (long)blockIdx.x*32;
  const float* src = input + pbase*256;
  float4 xv[8];
  #pragma unroll
  for (int i=0;i<8;i++) xv[i] = ld4(src + i*1024 + t*4);
  #pragma unroll
  for (int i=0;i<8;i++){
    int e = i*1024 + t*4;
    int row = e>>8, k = e&255;
    ushort4 u;
    u.x = f2bf(xv[i].x); u.y = f2bf(xv[i].y); u.z = f2bf(xv[i].z); u.w = f2bf(xv[i].w);
    unsigned byteoff = (unsigned)((row*512 + k*2) ^ ((row&7)<<4));
    *reinterpret_cast<ushort4*>(reinterpret_cast<char*>(sm) + byteoff) = u;
  }
  __syncthreads();

  int l = t & 63, wv = t >> 6;
  int rl = l & 15, khi = l >> 4;
  unsigned xorv = (unsigned)((rl & 7) << 4);
  const unsigned short* wb = wt + (size_t)(wv*64 + rl)*256 + khi*8;

  f32x4 acc[2][4];
  #pragma unroll
  for (int m=0;m<2;m++)
    #pragma unroll
    for (int n=0;n<4;n++) acc[m][n] = (f32x4){0.f,0.f,0.f,0.f};

  #pragma unroll
  for (int kk=0; kk<8; ++kk){
    short8 a[2], bfr[4];
    #pragma unroll
    for (int m=0;m<2;m++){
      unsigned off = (unsigned)(((m*16+rl)*512 + (kk*32 + khi*8)*2) ^ xorv);
      a[m] = *reinterpret_cast<const short8*>(reinterpret_cast<const char*>(sm) + off);
    }
    #pragma unroll
    for (int n=0;n<4;n++)
      bfr[n] = *reinterpret_cast<const short8*>(wb + n*16*256 + kk*32);
    #pragma unroll
    for (int m=0;m<2;m++)
      #pragma unroll
      for (int n=0;n<4;n++)
        acc[m][n] = __builtin_amdgcn_mfma_f32_16x16x32_bf16(a[m], bfr[n], acc[m][n], 0, 0, 0);
  }

  __syncthreads();                           // reuse sm for output transpose (stride 260)
  #pragma unroll
  for (int m=0;m<2;m++)
    #pragma unroll
    for (int n=0;n<4;n++){
      int col = wv*64 + n*16 + rl;
      #pragma unroll
      for (int i=0;i<4;i++){
        int row = m*16 + khi*4 + i;
        sm[row*260 + col] = f2bf(acc[m][n][i]);
      }
    }
  __syncthreads();
  #pragma unroll
  for (int i=0;i<2;i++){
    int row = (t>>4) + i*16;
    const unsigned short* sp = sm + row*260 + (t&15)*16;
    short8 v0 = *reinterpret_cast<const short8*>(sp);
    short8 v1 = *reinterpret_cast<const short8*>(sp+8);
    unsigned short* dst = pixb + (pbase+row)*256 + (t&15)*16;
    *reinterpret_cast<short8*>(dst)   = v0;
    *reinterpret_cast<short8*>(dst+8) = v1;
  }
}

// ---------------- h1: barrier-free gather + layer-1 tail -> h1b (bf16) ----------------
// thread = (voxel, quarter): 8 independent 16B gathers in flight per thread.
__global__ __launch_bounds__(256) void h1_kernel(
    const float4* __restrict__ nb, const unsigned short* __restrict__ pixb,
    const float* __restrict__ w1, const float* __restrict__ b1,
    unsigned short* __restrict__ h1b)
{
  int gid = blockIdx.x*256 + threadIdx.x;    // 0 .. NVOX*4-1
  int v = gid>>2, q = gid&3;
  int o0 = q*32;                             // this thread owns cols [o0, o0+32)
  float4 n0 = nb[(size_t)v*2], n1 = nb[(size_t)v*2+1];
  int i0 = __float_as_int(n0.x), i1 = __float_as_int(n1.x);
  short8 pA[4], pB[4];
  #pragma unroll
  for (int j=0;j<4;j++){
    pA[j] = *reinterpret_cast<const short8*>(pixb + (size_t)i0*256 + o0 + j*8);
    pB[j] = *reinterpret_cast<const short8*>(pixb + (size_t)i1*256 + 128 + o0 + j*8);
  }
  #pragma unroll
  for (int j=0;j<4;j++){
    int o = o0 + j*8;
    const float* wd = w1 + 256*128 + o;      // dist rows k=0: 256..258
    const float* we = w1 + 515*128 + o;      // dist rows k=1: 515..517
    union { short8 s; unsigned short u[8]; } pk;
    #pragma unroll
    for (int e=0;e<8;e++){
      float x = bf2f((unsigned short)pA[j][e]) + bf2f((unsigned short)pB[j][e]);
      x = fmaf(n0.y, wd[e],     x);
      x = fmaf(n0.z, wd[128+e], x);
      x = fmaf(n0.w, wd[256+e], x);
      x = fmaf(n1.y, we[e],     x);
      x = fmaf(n1.z, we[128+e], x);
      x = fmaf(n1.w, we[256+e], x);
      x += b1[o+e];
      pk.u[e] = f2bf(fmaxf(x, 0.f));
    }
    *reinterpret_cast<short8*>(h1b + (size_t)v*128 + o) = pk.s;
  }
}

// ---------------- mlp2: MFMA layers 2+3, conv scatter-add epilogue ----------------
// block = 128 voxel rows (4 waves x 32). All 8 a-loads hoisted for MLP;
// h2 = relu(h1@w2+b2) in-register; conv_w[k]*(s+b3) scatter-added into y.
__global__ __launch_bounds__(256) void mlp2_kernel(
    const unsigned short* __restrict__ h1b, const unsigned short* __restrict__ w2t,
    const float* __restrict__ b2, const float* __restrict__ w3,
    const float* __restrict__ b3, const float* __restrict__ conv_w,
    float* __restrict__ y)
{
  int t = threadIdx.x;
  int l = t&63, wv = t>>6;
  int rl = l&15, khi = l>>4;
  int rowbase = blockIdx.x*128 + wv*32;

  // hoist ALL a-loads: 8 x 16B in flight
  short8 a[2][4];
  #pragma unroll
  for (int m=0;m<2;m++)
    #pragma unroll
    for (int kk=0;kk<4;kk++)
      a[m][kk] = *reinterpret_cast<const short8*>(h1b + (size_t)(rowbase + m*16 + rl)*128 + kk*32 + khi*8);

  f32x4 acc[2][4];
  #pragma unroll
  for (int m=0;m<2;m++)
    #pragma unroll
    for (int n=0;n<4;n++) acc[m][n] = (f32x4){0.f,0.f,0.f,0.f};

  #pragma unroll
  for (int kk=0; kk<4; ++kk){
    short8 bfr[4];
    #pragma unroll
    for (int n=0;n<4;n++)
      bfr[n] = *reinterpret_cast<const short8*>(w2t + (size_t)(n*16 + rl)*128 + kk*32 + khi*8);
    #pragma unroll
    for (int m=0;m<2;m++)
      #pragma unroll
      for (int n=0;n<4;n++)
        acc[m][n] = __builtin_amdgcn_mfma_f32_16x16x32_bf16(a[m][kk], bfr[n], acc[m][n], 0, 0, 0);
  }

  float b2v[4], w3v[4];
  #pragma unroll
  for (int n=0;n<4;n++){ b2v[n] = b2[n*16+rl]; w3v[n] = w3[n*16+rl]; }
  float bias3 = b3[0];
  #pragma unroll
  for (int m=0;m<2;m++){
    #pragma unroll
    for (int i=0;i<4;i++){
      float s = 0.f;
      #pragma unroll
      for (int n=0;n<4;n++)
        s = fmaf(fmaxf(acc[m][n][i] + b2v[n], 0.f), w3v[n], s);
      s += __shfl_xor(s, 1);
      s += __shfl_xor(s, 2);
      s += __shfl_xor(s, 4);
      s += __shfl_xor(s, 8);
      if (rl == 0){
        int v = rowbase + m*16 + khi*4 + i;      // global voxel id
        int c  = v & 31;
        int k  = (v >> 5) & 31;
        int j  = (v >> 10) & 63;
        int ib = v >> 16;
        int tt = (((c<<1) | ib) << 6) | j;
        atomicAdd(&y[tt], conv_w[k] * (s + bias3));
      }
    }
  }
}

extern "C" void kernel_launch(void* const* d_in, const int* in_sizes, int n_in,
                              void* d_out, int out_size, void* d_ws, size_t ws_size,
                              hipStream_t stream)
{
  const float* input  = (const float*)d_in[0];
  const float* kdtree = (const float*)d_in[1];
  const float* Tr     = (const float*)d_in[2];
  const float* R0     = (const float*)d_in[3];
  const float* P3     = (const float*)d_in[4];
  const float* w1     = (const float*)d_in[5];
  const float* b1     = (const float*)d_in[6];
  const float* w2     = (const float*)d_in[7];
  const float* b2     = (const float*)d_in[8];
  const float* w3     = (const float*)d_in[9];
  const float* b3     = (const float*)d_in[10];
  const float* conv_w = (const float*)d_in[11];
  const float* conv_b = (const float*)d_in[12];

  char* wsb = (char*)d_ws;
  unsigned short* pixb = (unsigned short*)wsb;                  // 15,728,640 B
  float4* nb           = (float4*)(wsb + 15728640);             //  4,194,304 B
  unsigned short* h1b  = (unsigned short*)(wsb + 19922944);     // 33,554,432 B
  unsigned short* wt   = (unsigned short*)(wsb + 53477376);     //    131,072 B
  unsigned short* w2t  = (unsigned short*)(wsb + 53608448);     //     16,384 B
  float* y = (float*)d_out;

  hipLaunchKernelGGL(setup_all,  dim3(1328),        dim3(256), 0, stream,
                     P3, R0, Tr, w1, w2, conv_b, kdtree, wt, w2t, nb, y);
  hipLaunchKernelGGL(pix_mfma,   dim3(NPIX/32),     dim3(256), 0, stream, input, wt, pixb);
  hipLaunchKernelGGL(h1_kernel,  dim3(NVOX*4/256),  dim3(256), 0, stream, nb, pixb, w1, b1, h1b);
  hipLaunchKernelGGL(mlp2_kernel,dim3(NVOX/128),    dim3(256), 0, stream, h1b, w2t, b2, w3, b3, conv_w, y);
}

// Round 12
// 202.881 us; speedup vs baseline: 1.2765x; 1.2765x over previous
//
#include <hip/hip_runtime.h>

#define HH 64
#define WWID 64
#define CCH 32
#define HFD 96
#define WFD 320
#define NPIX (HFD*WFD)      // 30720
#define NVOX (HH*WWID*CCH)  // 131072

typedef __attribute__((ext_vector_type(8))) short short8;   // 8 bf16 (4 VGPRs)
typedef __attribute__((ext_vector_type(4))) float f32x4;

__device__ __forceinline__ float4 ld4(const float* p){ return *reinterpret_cast<const float4*>(p); }
__device__ __forceinline__ unsigned short f2bf(float f){   // RNE f32 -> bf16
  unsigned int u = __float_as_uint(f);
  return (unsigned short)((u + 0x7FFFu + ((u>>16)&1u)) >> 16);
}
__device__ __forceinline__ float bf2f(unsigned short s){
  return __uint_as_float(((unsigned int)s) << 16);
}

// ---------------- setup_all: weight tables + y-init + projection ----------------
// b in [0,256):    wt[n][k] (256x256): n<128 -> w1[k][n] ; n>=128 -> w1[259+k][n-128]
// b in [256,288):  w2t[c][k] (64x128) = w2[k][c]
// b in [288,304):  y[idx] = conv_b[0]   (4096 outputs)
// b >= 304:        projection for (v,k) pairs -> nb (1024 blocks)
__global__ __launch_bounds__(256) void setup_all(
    const float* __restrict__ P3, const float* __restrict__ R0,
    const float* __restrict__ Tr, const float* __restrict__ w1,
    const float* __restrict__ w2, const float* __restrict__ conv_b,
    const float* __restrict__ kdtree,
    unsigned short* __restrict__ wt, unsigned short* __restrict__ w2t,
    float4* __restrict__ nb, float* __restrict__ y)
{
  int b = blockIdx.x, t = threadIdx.x;
  if (b < 256){
    int e = b*256 + t;
    int n = e>>8, k = e&255;
    float v = (n<128) ? w1[k*128 + n] : w1[(259+k)*128 + (n-128)];
    wt[n*256 + k] = f2bf(v);
  } else if (b < 288){
    int e2 = (b-256)*256 + t;                // 0..8191
    int c = e2>>7, k = e2&127;
    w2t[c*128 + k] = f2bf(w2[k*64 + c]);
  } else if (b < 304){
    int idx = (b-288)*256 + t;               // 0..4095
    y[idx] = conv_b[0];
  } else {
    // projection: M computed per-block by 12 lanes (double), broadcast via LDS
    __shared__ double Ms[12];
    if (t < 12){
      int e3 = t>>2, d = t&3;
      double PRr[4];
      #pragma unroll
      for (int bb=0;bb<4;bb++){
        double s = 0.0;
        #pragma unroll
        for (int a=0;a<4;a++) s += (double)P3[e3*4+a]*(double)R0[a*4+bb];
        PRr[bb] = s;
      }
      double s = 0.0;
      #pragma unroll
      for (int bb=0;bb<4;bb++) s += PRr[bb]*(double)Tr[bb*4+d];
      Ms[t] = s;
    }
    __syncthreads();
    int gid = (b-304)*256 + t;               // 0 .. NVOX*2-1
    int v = gid>>1, k = gid&1;
    int c = v&31, w = (v>>5)&63, h = v>>11;
    size_t off = ((((size_t)(h*4)*256 + (size_t)(w*4))*32 + c)*2 + k)*4;
    float4 kp = ld4(kdtree + off);
    double k0 = kp.x, k1 = kp.y, k2 = kp.z;
    double cam0 = Ms[0]*k0 + Ms[1]*k1 + Ms[2]*k2  + Ms[3];
    double cam1 = Ms[4]*k0 + Ms[5]*k1 + Ms[6]*k2  + Ms[7];
    double cam2 = Ms[8]*k0 + Ms[9]*k1 + Ms[10]*k2 + Ms[11];
    float zf = (float)cam2;
    double zd = (fabsf(zf) < 1e-6f) ? (double)1e-6f : cam2;
    double rz = 1.0/zd;
    int ty = (int)(cam1*rz), tx = (int)(cam0*rz);   // trunc, matches astype(int32)
    int iy = ty < 0 ? 0 : ((ty>>2) > (HFD-1) ? (HFD-1) : (ty>>2));
    int ix = tx < 0 ? 0 : ((tx>>2) > (WFD-1) ? (WFD-1) : (tx>>2));
    float4 r;
    r.x = __int_as_float(iy*WFD + ix);
    r.y = kp.x - 1.0f;
    r.z = kp.y - (float)(h*4);
    r.w = kp.z - (float)(w*4);
    nb[gid] = r;
  }
}

// ---------------- pix: bf16 MFMA GEMM, pixb[30720x256](bf16) = X @ W' ----------------
// 32-row tiles (960 blocks for TLP), K=256 staged in LDS (XOR-swizzled), 4 waves split N.
__global__ __launch_bounds__(256) void pix_mfma(
    const float* __restrict__ input, const unsigned short* __restrict__ wt,
    unsigned short* __restrict__ pixb)
{
  __shared__ unsigned short sm[32*260];      // 16.6 KB: staging (16 KB swz) / epilogue 32x260
  int t = threadIdx.x;
  long pbase = (long)blockIdx.x*32;
  const float* src = input + pbase*256;
  float4 xv[8];
  #pragma unroll
  for (int i=0;i<8;i++) xv[i] = ld4(src + i*1024 + t*4);
  #pragma unroll
  for (int i=0;i<8;i++){
    int e = i*1024 + t*4;
    int row = e>>8, k = e&255;
    ushort4 u;
    u.x = f2bf(xv[i].x); u.y = f2bf(xv[i].y); u.z = f2bf(xv[i].z); u.w = f2bf(xv[i].w);
    unsigned byteoff = (unsigned)((row*512 + k*2) ^ ((row&7)<<4));
    *reinterpret_cast<ushort4*>(reinterpret_cast<char*>(sm) + byteoff) = u;
  }
  __syncthreads();

  int l = t & 63, wv = t >> 6;
  int rl = l & 15, khi = l >> 4;
  unsigned xorv = (unsigned)((rl & 7) << 4);
  const unsigned short* wb = wt + (size_t)(wv*64 + rl)*256 + khi*8;

  f32x4 acc[2][4];
  #pragma unroll
  for (int m=0;m<2;m++)
    #pragma unroll
    for (int n=0;n<4;n++) acc[m][n] = (f32x4){0.f,0.f,0.f,0.f};

  #pragma unroll
  for (int kk=0; kk<8; ++kk){
    short8 a[2], bfr[4];
    #pragma unroll
    for (int m=0;m<2;m++){
      unsigned off = (unsigned)(((m*16+rl)*512 + (kk*32 + khi*8)*2) ^ xorv);
      a[m] = *reinterpret_cast<const short8*>(reinterpret_cast<const char*>(sm) + off);
    }
    #pragma unroll
    for (int n=0;n<4;n++)
      bfr[n] = *reinterpret_cast<const short8*>(wb + n*16*256 + kk*32);
    #pragma unroll
    for (int m=0;m<2;m++)
      #pragma unroll
      for (int n=0;n<4;n++)
        acc[m][n] = __builtin_amdgcn_mfma_f32_16x16x32_bf16(a[m], bfr[n], acc[m][n], 0, 0, 0);
  }

  __syncthreads();                           // reuse sm for output transpose (stride 260)
  #pragma unroll
  for (int m=0;m<2;m++)
    #pragma unroll
    for (int n=0;n<4;n++){
      int col = wv*64 + n*16 + rl;
      #pragma unroll
      for (int i=0;i<4;i++){
        int row = m*16 + khi*4 + i;
        sm[row*260 + col] = f2bf(acc[m][n][i]);
      }
    }
  __syncthreads();
  #pragma unroll
  for (int i=0;i<2;i++){
    int row = (t>>4) + i*16;
    const unsigned short* sp = sm + row*260 + (t&15)*16;
    short8 v0 = *reinterpret_cast<const short8*>(sp);
    short8 v1 = *reinterpret_cast<const short8*>(sp+8);
    unsigned short* dst = pixb + (pbase+row)*256 + (t&15)*16;
    *reinterpret_cast<short8*>(dst)   = v0;
    *reinterpret_cast<short8*>(dst+8) = v1;
  }
}

// ---------------- mlp2f: in-register h1 (gather + layer-1 tail) + MFMA layers 2+3 + conv scatter ----------------
// block = 128 voxel rows (4 waves x 32 rows). Lane (rl,khi) gathers its own A-fragment
// sources: 16 independent 16B loads in flight; h1 never touches memory.
__global__ __launch_bounds__(256) void mlp2f_kernel(
    const float4* __restrict__ nb, const unsigned short* __restrict__ pixb,
    const float* __restrict__ w1, const float* __restrict__ b1,
    const unsigned short* __restrict__ w2t, const float* __restrict__ b2,
    const float* __restrict__ w3, const float* __restrict__ b3,
    const float* __restrict__ conv_w, float* __restrict__ y)
{
  int t = threadIdx.x;
  int l = t&63, wv = t>>6;
  int rl = l&15, khi = l>>4;
  int rowbase = blockIdx.x*128 + wv*32;

  // per-lane rows: r0 = rowbase+rl, r1 = rowbase+16+rl
  float4 n0a = nb[(size_t)(rowbase+rl)*2],    n1a = nb[(size_t)(rowbase+rl)*2+1];
  float4 n0b = nb[(size_t)(rowbase+16+rl)*2], n1b = nb[(size_t)(rowbase+16+rl)*2+1];
  int i0a = __float_as_int(n0a.x), i1a = __float_as_int(n1a.x);
  int i0b = __float_as_int(n0b.x), i1b = __float_as_int(n1b.x);

  // hoist all 16 gathers (cols c0 = kk*32 + khi*8)
  short8 pA[2][4], pB[2][4];
  #pragma unroll
  for (int kk=0;kk<4;kk++){
    int c0 = kk*32 + khi*8;
    pA[0][kk] = *reinterpret_cast<const short8*>(pixb + (size_t)i0a*256 + c0);
    pB[0][kk] = *reinterpret_cast<const short8*>(pixb + (size_t)i1a*256 + 128 + c0);
    pA[1][kk] = *reinterpret_cast<const short8*>(pixb + (size_t)i0b*256 + c0);
    pB[1][kk] = *reinterpret_cast<const short8*>(pixb + (size_t)i1b*256 + 128 + c0);
  }

  // layer-1 tail in-register -> bf16 A-fragments
  short8 a[2][4];
  #pragma unroll
  for (int kk=0;kk<4;kk++){
    int c0 = kk*32 + khi*8;
    const float* wd = w1 + 256*128 + c0;     // dist rows k=0: 256..258
    const float* we = w1 + 515*128 + c0;     // dist rows k=1: 515..517
    float wd0[8], wd1[8], wd2[8], we0[8], we1[8], we2[8], bb[8];
    #pragma unroll
    for (int e=0;e<8;e++){
      wd0[e]=wd[e]; wd1[e]=wd[128+e]; wd2[e]=wd[256+e];
      we0[e]=we[e]; we1[e]=we[128+e]; we2[e]=we[256+e];
      bb[e]=b1[c0+e];
    }
    #pragma unroll
    for (int m=0;m<2;m++){
      float4 n0 = (m==0)?n0a:n0b, n1 = (m==0)?n1a:n1b;
      union { short8 s; unsigned short u[8]; } pk;
      #pragma unroll
      for (int e=0;e<8;e++){
        float x = bf2f((unsigned short)pA[m][kk][e]) + bf2f((unsigned short)pB[m][kk][e]);
        x = fmaf(n0.y, wd0[e], x);
        x = fmaf(n0.z, wd1[e], x);
        x = fmaf(n0.w, wd2[e], x);
        x = fmaf(n1.y, we0[e], x);
        x = fmaf(n1.z, we1[e], x);
        x = fmaf(n1.w, we2[e], x);
        x += bb[e];
        pk.u[e] = f2bf(fmaxf(x, 0.f));
      }
      a[m][kk] = pk.s;
    }
  }

  // MFMA layers 2 (128->64)
  f32x4 acc[2][4];
  #pragma unroll
  for (int m=0;m<2;m++)
    #pragma unroll
    for (int n=0;n<4;n++) acc[m][n] = (f32x4){0.f,0.f,0.f,0.f};

  #pragma unroll
  for (int kk=0; kk<4; ++kk){
    short8 bfr[4];
    #pragma unroll
    for (int n=0;n<4;n++)
      bfr[n] = *reinterpret_cast<const short8*>(w2t + (size_t)(n*16 + rl)*128 + kk*32 + khi*8);
    #pragma unroll
    for (int m=0;m<2;m++)
      #pragma unroll
      for (int n=0;n<4;n++)
        acc[m][n] = __builtin_amdgcn_mfma_f32_16x16x32_bf16(a[m][kk], bfr[n], acc[m][n], 0, 0, 0);
  }

  // layer 3 + conv scatter-add
  float b2v[4], w3v[4];
  #pragma unroll
  for (int n=0;n<4;n++){ b2v[n] = b2[n*16+rl]; w3v[n] = w3[n*16+rl]; }
  float bias3 = b3[0];
  #pragma unroll
  for (int m=0;m<2;m++){
    #pragma unroll
    for (int i=0;i<4;i++){
      float s = 0.f;
      #pragma unroll
      for (int n=0;n<4;n++)
        s = fmaf(fmaxf(acc[m][n][i] + b2v[n], 0.f), w3v[n], s);
      s += __shfl_xor(s, 1);
      s += __shfl_xor(s, 2);
      s += __shfl_xor(s, 4);
      s += __shfl_xor(s, 8);
      if (rl == 0){
        int v = rowbase + m*16 + khi*4 + i;      // global voxel id
        int c  = v & 31;
        int k  = (v >> 5) & 31;
        int j  = (v >> 10) & 63;
        int ib = v >> 16;
        int tt = (((c<<1) | ib) << 6) | j;
        atomicAdd(&y[tt], conv_w[k] * (s + bias3));
      }
    }
  }
}

extern "C" void kernel_launch(void* const* d_in, const int* in_sizes, int n_in,
                              void* d_out, int out_size, void* d_ws, size_t ws_size,
                              hipStream_t stream)
{
  const float* input  = (const float*)d_in[0];
  const float* kdtree = (const float*)d_in[1];
  const float* Tr     = (const float*)d_in[2];
  const float* R0     = (const float*)d_in[3];
  const float* P3     = (const float*)d_in[4];
  const float* w1     = (const float*)d_in[5];
  const float* b1     = (const float*)d_in[6];
  const float* w2     = (const float*)d_in[7];
  const float* b2     = (const float*)d_in[8];
  const float* w3     = (const float*)d_in[9];
  const float* b3     = (const float*)d_in[10];
  const float* conv_w = (const float*)d_in[11];
  const float* conv_b = (const float*)d_in[12];

  char* wsb = (char*)d_ws;
  unsigned short* pixb = (unsigned short*)wsb;                  // 15,728,640 B
  float4* nb           = (float4*)(wsb + 15728640);             //  4,194,304 B
  unsigned short* wt   = (unsigned short*)(wsb + 19922944);     //    131,072 B
  unsigned short* w2t  = (unsigned short*)(wsb + 20054016);     //     16,384 B
  float* y = (float*)d_out;

  hipLaunchKernelGGL(setup_all,   dim3(1328),      dim3(256), 0, stream,
                     P3, R0, Tr, w1, w2, conv_b, kdtree, wt, w2t, nb, y);
  hipLaunchKernelGGL(pix_mfma,    dim3(NPIX/32),   dim3(256), 0, stream, input, wt, pixb);
  hipLaunchKernelGGL(mlp2f_kernel,dim3(NVOX/128),  dim3(256), 0, stream,
                     nb, pixb, w1, b1, w2t, b2, w3, b3, conv_w, y);
}